// Round 3
// baseline (2260.742 us; speedup 1.0000x reference)
//
#include <hip/hip_runtime.h>
#include <hip/hip_bf16.h>

// Problem dims (fixed by reference)
#define BB 2
#define LL 1024
#define DM 768
#define ED 1536
#define NTOK 2048        // BB*LL
#define DSTATE 16
#define DTRANK 48
#define VOCAB 32000

typedef unsigned short ushort_t;
typedef __attribute__((ext_vector_type(8))) short short8;   // 8 bf16 bits = 4 VGPRs (A/B frag)
typedef __attribute__((ext_vector_type(4))) float f32x4;    // C/D frag

__device__ __forceinline__ ushort_t f2bf(float f) {
    __hip_bfloat16 h = __float2bfloat16(f);
    return *(ushort_t*)&h;
}
__device__ __forceinline__ float silu(float x) { return x / (1.f + expf(-x)); }

// ---------------- embedding gather: x[t,:] = emb[ids[t],:] (f32) ----------------
__global__ void embed_kernel(const int* __restrict__ ids, const float* __restrict__ emb,
                             float* __restrict__ x) {
    int t = blockIdx.x;
    const float* src = emb + (size_t)ids[t] * DM;
    float* dst = x + (size_t)t * DM;
    for (int c = threadIdx.x; c < DM; c += blockDim.x) dst[c] = src[c];
}

// ---------------- rmsnorm over D (f32 in), emit bf16 for GEMM A-operand ----------------
__global__ void rmsnorm_kernel(const float* __restrict__ x, const float* __restrict__ w,
                               ushort_t* __restrict__ out, int D) {
    int t = blockIdx.x;
    const float* xr = x + (size_t)t * D;
    float ss = 0.f;
    for (int c = threadIdx.x; c < D; c += blockDim.x) { float v = xr[c]; ss += v * v; }
    #pragma unroll
    for (int o = 32; o > 0; o >>= 1) ss += __shfl_down(ss, o, 64);
    __shared__ float s[4];
    int wid = threadIdx.x >> 6;
    if ((threadIdx.x & 63) == 0) s[wid] = ss;
    __syncthreads();
    float rs = rsqrtf((s[0] + s[1] + s[2] + s[3]) / (float)D + 1e-5f);
    ushort_t* orow = out + (size_t)t * D;
    for (int c = threadIdx.x; c < D; c += blockDim.x)
        orow[c] = f2bf(xr[c] * rs * w[c]);
}

// ---------------- MFMA GEMM: out(MxN,f32) = A(MxK,bf16) * W(NxK,f32)^T [+ X(f32)] ----------
// 128x128 tile, BK=32, 4 waves each 4x4 of 16x16x32 mfma. M%128==0, N%128==0, K%32==0.
// B-staging converts fp32 weights -> bf16 into LDS on the fly.
template<bool RESID>
__global__ __launch_bounds__(256) void gemm_bt(const ushort_t* __restrict__ A,
                                               const float* __restrict__ W,
                                               const float* X,
                                               float* out,
                                               int M, int N, int K) {
    __shared__ __align__(16) ushort_t As[128][40];   // +8 pad: 80B row stride (16B-aligned rows)
    __shared__ __align__(16) ushort_t Bs[128][40];
    const int n0 = blockIdx.x * 128;
    const int m0 = blockIdx.y * 128;
    const int tid = threadIdx.x;
    const int w = tid >> 6, lane = tid & 63;
    const int wm = (w >> 1) * 64, wn = (w & 1) * 64;
    const int lrow = lane & 15, koff = (lane >> 4) * 8;
    const int sr = tid >> 2, sc = (tid & 3) * 8;

    f32x4 acc[4][4] = {};

    for (int k0 = 0; k0 < K; k0 += 32) {
        __syncthreads();
        // A: bf16 source, direct 16B copies (128 rows x 32 cols)
        *(uint4*)&As[sr][sc]      = *(const uint4*)&A[(size_t)(m0 + sr) * K + k0 + sc];
        *(uint4*)&As[sr + 64][sc] = *(const uint4*)&A[(size_t)(m0 + sr + 64) * K + k0 + sc];
        // B: fp32 source, float4 load -> 4x bf16 convert -> 8B LDS store
        #pragma unroll
        for (int it = 0; it < 4; ++it) {
            int chunk = tid + it * 256;            // 1024 chunks = 128 rows x 8 float4
            int row = chunk >> 3, col = (chunk & 7) * 4;
            float4 f = *(const float4*)&W[(size_t)(n0 + row) * K + k0 + col];
            ushort4 u;
            u.x = f2bf(f.x); u.y = f2bf(f.y); u.z = f2bf(f.z); u.w = f2bf(f.w);
            *(ushort4*)&Bs[row][col] = u;
        }
        __syncthreads();
        short8 af[4], bfr[4];
        #pragma unroll
        for (int t = 0; t < 4; ++t) af[t]  = *(const short8*)&As[wm + t * 16 + lrow][koff];
        #pragma unroll
        for (int t = 0; t < 4; ++t) bfr[t] = *(const short8*)&Bs[wn + t * 16 + lrow][koff];
        #pragma unroll
        for (int tm = 0; tm < 4; ++tm)
            #pragma unroll
            for (int tn = 0; tn < 4; ++tn)
                acc[tm][tn] = __builtin_amdgcn_mfma_f32_16x16x32_bf16(af[tm], bfr[tn], acc[tm][tn], 0, 0, 0);
    }

    const int kq4 = (lane >> 4) * 4;   // C/D: col = lane&15, row = (lane>>4)*4 + i  [verified m89/m91]
    #pragma unroll
    for (int tm = 0; tm < 4; ++tm) {
        #pragma unroll
        for (int tn = 0; tn < 4; ++tn) {
            const int c  = n0 + wn + tn * 16 + lrow;
            const int rb = m0 + wm + tm * 16 + kq4;
            #pragma unroll
            for (int i = 0; i < 4; ++i) {
                size_t off = (size_t)(rb + i) * N + c;
                float v = acc[tm][tn][i];
                if (RESID) v += X[off];
                out[off] = v;
            }
        }
    }
}

// ---------------- causal depthwise conv (D_CONV=4) + bias + silu ----------------
__global__ void conv_silu_kernel(const float* __restrict__ xz, const float* __restrict__ cw,
                                 const float* __restrict__ cb, float* __restrict__ xi) {
    int idx = blockIdx.x * blockDim.x + threadIdx.x;   // NTOK*ED
    int c = idx % ED;
    int t = idx / ED;
    int l = t % LL;
    float acc = cb[c];
    #pragma unroll
    for (int k = 0; k < 4; ++k) {
        int ls = l + k - 3;
        if (ls >= 0) acc += xz[(size_t)(t + k - 3) * (2 * ED) + c] * cw[c * 4 + k];
    }
    xi[idx] = silu(acc);
}

// ---------------- x_proj: dbc(NTOK,80) = xi(NTOK,ED) @ wx(80,ED)^T ----------------
__global__ void xproj_kernel(const float* __restrict__ xi, const float* __restrict__ wx,
                             float* __restrict__ dbc) {
    int t = blockIdx.x;
    __shared__ float sx[ED];
    const float* xr = xi + (size_t)t * ED;
    for (int c = threadIdx.x; c < ED; c += blockDim.x) sx[c] = xr[c];
    __syncthreads();
    int w = threadIdx.x >> 6, lane = threadIdx.x & 63;
    for (int j = w; j < DTRANK + 2 * DSTATE; j += 4) {
        const float* wr = wx + (size_t)j * ED;
        float s = 0.f;
        for (int k = lane; k < ED; k += 64) s += sx[k] * wr[k];
        #pragma unroll
        for (int o = 32; o > 0; o >>= 1) s += __shfl_down(s, o, 64);
        if (lane == 0) dbc[(size_t)t * 80 + j] = s;
    }
}

// ---------------- dt proj + softplus: delta(NTOK,ED) ----------------
__global__ void dtproj_kernel(const float* __restrict__ dbc, const float* __restrict__ wdt,
                              const float* __restrict__ bdt, float* __restrict__ delta) {
    int t = blockIdx.x;
    __shared__ float sdr[DTRANK];
    if (threadIdx.x < DTRANK) sdr[threadIdx.x] = dbc[(size_t)t * 80 + threadIdx.x];
    __syncthreads();
    for (int e = threadIdx.x; e < ED; e += blockDim.x) {
        const float* wr = wdt + (size_t)e * DTRANK;
        float acc = bdt[e];
        #pragma unroll
        for (int r = 0; r < DTRANK; ++r) acc += sdr[r] * wr[r];
        delta[(size_t)t * ED + e] = (acc > 20.f) ? acc : log1pf(expf(acc));
    }
}

// ---------------- selective scan (with fused skip_D*xi) ----------------
// wave = 4 channels x 16 states. lane: e = eb + (lane>>4), n = lane&15.
__global__ void scan_kernel(const float* __restrict__ delta, const float* __restrict__ xi,
                            const float* __restrict__ dbc, const float* __restrict__ a_log,
                            const float* __restrict__ skd, float* __restrict__ y) {
    int b = blockIdx.y;
    int w = threadIdx.x >> 6, lane = threadIdx.x & 63;
    int n = lane & 15;
    int e = blockIdx.x * 16 + w * 4 + (lane >> 4);
    float Ae = -expf(a_log[e * DSTATE + n]);
    float skip = skd[e];
    float h = 0.f;
    size_t tb = (size_t)b * LL;
    for (int l = 0; l < LL; ++l) {
        size_t row = tb + l;
        float dl = delta[row * ED + e];
        float xv = xi[row * ED + e];
        float Bv = dbc[row * 80 + DTRANK + n];
        float Cv = dbc[row * 80 + DTRANK + DSTATE + n];
        float dA = __expf(dl * Ae);
        h = dA * h + dl * xv * Bv;
        float p = h * Cv;
        p += __shfl_xor(p, 1, 16);
        p += __shfl_xor(p, 2, 16);
        p += __shfl_xor(p, 4, 16);
        p += __shfl_xor(p, 8, 16);
        if (n == 0) y[row * ED + e] = p + skip * xv;   // fused y + skip_D*xi
    }
}

// ---------------- gate: yz = y_tot * silu(z), emit bf16 ----------------
__global__ void gate_kernel(const float* __restrict__ y, const float* __restrict__ xz,
                            ushort_t* __restrict__ yzb) {
    int idx = blockIdx.x * blockDim.x + threadIdx.x;   // NTOK*ED
    int c = idx % ED;
    int t = idx / ED;
    float z = xz[(size_t)t * (2 * ED) + ED + c];
    yzb[idx] = f2bf(y[idx] * silu(z));
}

extern "C" void kernel_launch(void* const* d_in, const int* in_sizes, int n_in,
                              void* d_out, int out_size, void* d_ws, size_t ws_size,
                              hipStream_t stream) {
    const int*   ids      = (const int*)d_in[0];
    const float* emb      = (const float*)d_in[1];
    const float* ln_w     = (const float*)d_in[2];
    const float* in_proj  = (const float*)d_in[3];
    const float* conv_w   = (const float*)d_in[4];
    const float* conv_b   = (const float*)d_in[5];
    const float* x_proj   = (const float*)d_in[6];
    const float* dt_w     = (const float*)d_in[7];
    const float* dt_b     = (const float*)d_in[8];
    const float* A_log    = (const float*)d_in[9];
    const float* skip_D   = (const float*)d_in[10];
    const float* out_proj = (const float*)d_in[11];
    const float* normf_w  = (const float*)d_in[12];
    const float* lm_head  = (const float*)d_in[13];

    char* ws = (char*)d_ws;
    float*    x     = (float*)(ws);                                   // NTOK*DM f32   (6.29 MB)
    ushort_t* h_bf  = (ushort_t*)(ws + 6291456);                      // NTOK*DM bf16  (3.15 MB)
    float*    xz    = (float*)(ws + 9437184);                         // NTOK*2ED f32  (25.2 MB)
    float*    xi    = (float*)(ws + 34603008);                        // NTOK*ED f32   (12.6 MB)
    float*    dbc   = (float*)(ws + 47185920);                        // NTOK*80 f32   (0.66 MB)
    float*    delta = (float*)(ws + 47841280);                        // NTOK*ED f32   (12.6 MB)
    float*    y     = (float*)(ws + 60424192);                        // NTOK*ED f32   (12.6 MB)
    ushort_t* yzb   = (ushort_t*)(ws + 73007104);                     // NTOK*ED bf16  (6.29 MB)
    const size_t WS_NEED = 79298560;                                  // ~79.3 MB total
    if (ws_size < WS_NEED) return;   // defensive: avoid OOB writes wedging the GPU

    embed_kernel<<<NTOK, 256, 0, stream>>>(ids, emb, x);

    for (int i = 0; i < 2; ++i) {
        const float* lw   = ln_w + (size_t)i * DM;
        const float* wip  = in_proj + (size_t)i * 2 * ED * DM;
        const float* cw   = conv_w + (size_t)i * ED * 4;
        const float* cb   = conv_b + (size_t)i * ED;
        const float* wx   = x_proj + (size_t)i * 80 * ED;
        const float* wdt  = dt_w + (size_t)i * ED * DTRANK;
        const float* bdt  = dt_b + (size_t)i * ED;
        const float* alog = A_log + (size_t)i * ED * DSTATE;
        const float* skd  = skip_D + (size_t)i * ED;
        const float* wo   = out_proj + (size_t)i * DM * ED;

        rmsnorm_kernel<<<NTOK, 256, 0, stream>>>(x, lw, h_bf, DM);
        gemm_bt<false><<<dim3(2 * ED / 128, NTOK / 128), 256, 0, stream>>>(
            h_bf, wip, nullptr, xz, NTOK, 2 * ED, DM);
        conv_silu_kernel<<<NTOK * ED / 256, 256, 0, stream>>>(xz, cw, cb, xi);
        xproj_kernel<<<NTOK, 256, 0, stream>>>(xi, wx, dbc);
        dtproj_kernel<<<NTOK, 256, 0, stream>>>(dbc, wdt, bdt, delta);
        scan_kernel<<<dim3(ED / 16, BB), 256, 0, stream>>>(delta, xi, dbc, alog, skd, y);
        gate_kernel<<<NTOK * ED / 256, 256, 0, stream>>>(y, xz, yzb);
        gemm_bt<true><<<dim3(DM / 128, NTOK / 128), 256, 0, stream>>>(
            yzb, wo, x, x, NTOK, DM, ED);
    }

    rmsnorm_kernel<<<NTOK, 256, 0, stream>>>(x, normf_w, h_bf, DM);
    gemm_bt<false><<<dim3(VOCAB / 128, NTOK / 128), 256, 0, stream>>>(
        h_bf, lm_head, nullptr, (float*)d_out, NTOK, VOCAB, DM);
}